// Round 12
// baseline (340.332 us; speedup 1.0000x reference)
//
#include <hip/hip_runtime.h>
#include <hip/hip_bf16.h>

#define C_IN 10
#define C_OUT 64
#define BN_EPS 1e-3f

#define BPF   256         // pillars per bucket (idx>>8)
#define CB    256         // chunk blocks for hist/scatter
#define NBMAX 4704        // LDS histogram capacity
#define TS    2048        // scan tile size
#define MAXT  2048        // in-LDS fine-sort capacity (lambda=1280, +21 sigma)

typedef __attribute__((ext_vector_type(8))) short bf16x8;
typedef __attribute__((ext_vector_type(4))) float f32x4;

// ===========================================================================
// ATOMIC-FREE SORT PROLOGUE (4B records: lp<<22 | pointIdx)  — proven, ~35us
// ws (u32): ghist[NB*CB] (scanned in place) | tsum[nt] | bstart[NB+1] | rec[n]
// ===========================================================================

__global__ __launch_bounds__(1024) void k1_hist(const int* __restrict__ idx, int n, int chunk,
                                                unsigned* __restrict__ ghist, int NB, int shift) {
    __shared__ unsigned h[NBMAX];
    const int b = blockIdx.x, t = threadIdx.x;
    for (int i = t; i < NB; i += 1024) h[i] = 0u;
    __syncthreads();
    const int lo = b * chunk;
    const int hi = min(n, lo + chunk);
    for (int i = lo + t; i < hi; i += 1024)
        atomicAdd(&h[((unsigned)idx[i]) >> shift], 1u);
    __syncthreads();
    for (int k = t; k < NB; k += 1024)
        __builtin_nontemporal_store(h[k], &ghist[(size_t)k * CB + b]);
}

__global__ __launch_bounds__(256) void k2a_reduce(const unsigned* __restrict__ g, int G,
                                                  unsigned* __restrict__ tsum) {
    __shared__ unsigned s[256];
    const int t = threadIdx.x;
    const int base = blockIdx.x * TS + t * 8;
    unsigned acc = 0;
#pragma unroll
    for (int j = 0; j < 8; ++j) { int gi = base + j; if (gi < G) acc += g[gi]; }
    s[t] = acc; __syncthreads();
    for (int off = 128; off > 0; off >>= 1) { if (t < off) s[t] += s[t + off]; __syncthreads(); }
    if (t == 0) tsum[blockIdx.x] = s[0];
}

__global__ __launch_bounds__(256) void k2b_scan(unsigned* __restrict__ tsum, int nt) {
    __shared__ unsigned partial[256], basev[256];
    const int t = threadIdx.x;
    const int per = (nt + 255) / 256;
    const int lo = t * per, hi = min(nt, lo + per);
    unsigned s = 0;
    for (int i = lo; i < hi; ++i) s += tsum[i];
    partial[t] = s; __syncthreads();
    if (t == 0) { unsigned a = 0; for (int k = 0; k < 256; ++k) { basev[k] = a; a += partial[k]; } }
    __syncthreads();
    unsigned a = basev[t];
    for (int i = lo; i < hi; ++i) { unsigned v = tsum[i]; tsum[i] = a; a += v; }
}

__global__ __launch_bounds__(256) void k2c_apply(unsigned* __restrict__ g, int G,
                                                 const unsigned* __restrict__ tsum,
                                                 unsigned* __restrict__ bstart, int NB, int n) {
    __shared__ unsigned s[256];
    const int t = threadIdx.x;
    const int base = blockIdx.x * TS + t * 8;
    unsigned v[8]; unsigned acc = 0;
#pragma unroll
    for (int j = 0; j < 8; ++j) { int gi = base + j; v[j] = (gi < G) ? g[gi] : 0u; acc += v[j]; }
    s[t] = acc; __syncthreads();
    for (int off = 1; off < 256; off <<= 1) {
        unsigned x = (t >= off) ? s[t - off] : 0u; __syncthreads();
        s[t] += x; __syncthreads();
    }
    unsigned excl = ((t == 0) ? 0u : s[t - 1]) + tsum[blockIdx.x];
#pragma unroll
    for (int j = 0; j < 8; ++j) {
        int gi = base + j;
        if (gi < G) {
            g[gi] = excl;
            if ((gi & (CB - 1)) == 0) bstart[gi / CB] = excl;
            excl += v[j];
        }
    }
    if (blockIdx.x == 0 && t == 0) bstart[NB] = (unsigned)n;
}

__global__ __launch_bounds__(1024) void k3_scatter(const int* __restrict__ idx, int n, int chunk,
                                                   const unsigned* __restrict__ scanned,
                                                   unsigned* __restrict__ rec, int NB,
                                                   int shift, unsigned lpmask) {
    __shared__ unsigned cnt[NBMAX];
    __shared__ unsigned basel[NBMAX];
    const int b = blockIdx.x, t = threadIdx.x;
    for (int k = t; k < NB; k += 1024) { basel[k] = scanned[(size_t)k * CB + b]; cnt[k] = 0u; }
    __syncthreads();
    const int lo = b * chunk, hi = min(n, lo + chunk);
    for (int i = lo + t; i < hi; i += 1024) {
        unsigned pid = (unsigned)idx[i];
        unsigned k = pid >> shift;
        unsigned r = atomicAdd(&cnt[k], 1u);
        __builtin_nontemporal_store(((pid & lpmask) << 22) | (unsigned)i, &rec[basel[k] + r]);
    }
}

static __device__ __forceinline__ unsigned pk2(float2 v) {
    __hip_bfloat162 h = __float22bfloat162_rn(v);
    return *reinterpret_cast<unsigned*>(&h);
}

// ===========================================================================
// K4 v8: fine-sorted MFMA pool, 3-DEEP pipelined gather (2 outstanding
// pts-gathers per lane) + non-temporal output stores (keep L2 for the
// gather's line-sharing).
// ===========================================================================
__global__ __launch_bounds__(1024) void pool_sfm_kernel(
    const float* __restrict__ pts,
    const unsigned* __restrict__ rec,
    const unsigned* __restrict__ bstart,
    const float* __restrict__ W,
    const float* __restrict__ gamma, const float* __restrict__ beta,
    const float* __restrict__ mean, const float* __restrict__ var,
    float* __restrict__ out, int M)
{
    __shared__ unsigned smax[BPF * C_OUT];            // 64 KB
    __shared__ unsigned short ord[MAXT + 16];         // 4.1 KB
    __shared__ unsigned lps32[(MAXT + 16) / 4];       // 2.1 KB
    __shared__ unsigned cnt[BPF];                     // 1 KB
    __shared__ unsigned cur[BPF];                     // 1 KB
    __shared__ unsigned wsum[4];
    unsigned char* lpsb = (unsigned char*)lps32;

    const int b = blockIdx.x, t = threadIdx.x;
    const int lane = t & 63, w = t >> 6;              // w in 0..15
    const int g = lane >> 4, c0 = lane & 15;

    {
        uint4* s4 = (uint4*)smax;
        const uint4 z = make_uint4(0u, 0u, 0u, 0u);
        for (int i = t; i < BPF * C_OUT / 4; i += 1024) s4[i] = z;
    }
    if (t < BPF) cnt[t] = 0u;

    // B' = W*diag(scale), row k=10 = shift (A k10 = 1.0), rows 11..31 = 0
    bf16x8 bfrag[4];
#pragma unroll
    for (int tc = 0; tc < 4; ++tc) {
        const int ch = 16 * tc + c0;
        const float sc = gamma[ch] * rsqrtf(var[ch] + BN_EPS);
        const float sh = fmaf(-mean[ch], sc, beta[ch]);
        union { bf16x8 v; unsigned short u[8]; } B;
#pragma unroll
        for (int j = 0; j < 8; ++j) {
            const int k = g * 8 + j;
            float val = 0.f;
            if (k < 10) val = W[k * C_OUT + ch] * sc;
            else if (k == 10) val = sh;
            __hip_bfloat16 hb = __float2bfloat16(val);
            B.u[j] = *reinterpret_cast<unsigned short*>(&hb);
        }
        bfrag[tc] = B.v;
    }

    const unsigned base = bstart[b];
    const int T  = (int)(bstart[b + 1] - base);
    const int Tc = T < MAXT ? T : MAXT;
    __syncthreads();

    // ---- fine sort by local pillar ----
    int l0i = -1, l1i = -1;
    if (t < Tc)        { l0i = (int)(rec[base + t] >> 22);        atomicAdd(&cnt[l0i], 1u); }
    if (t + 1024 < Tc) { l1i = (int)(rec[base + t + 1024] >> 22); atomicAdd(&cnt[l1i], 1u); }
    __syncthreads();
    // exclusive scan of cnt[0..255] via 4-wave shfl scan (2 barriers)
    unsigned myv = 0, mys = 0;
    if (t < BPF) {
        myv = cnt[t];
        mys = myv;
#pragma unroll
        for (int off = 1; off < 64; off <<= 1) {
            unsigned y = (unsigned)__shfl_up((int)mys, off);
            if (lane >= off) mys += y;
        }
        if (lane == 63) wsum[t >> 6] = mys;
    }
    __syncthreads();
    if (t < BPF) {
        unsigned add = 0;
        const int mw = t >> 6;
        if (mw > 0) add += wsum[0];
        if (mw > 1) add += wsum[1];
        if (mw > 2) add += wsum[2];
        cur[t] = mys - myv + add;                     // exclusive scan
    }
    __syncthreads();
    if (l0i >= 0) { unsigned p = atomicAdd(&cur[l0i], 1u); ord[p] = (unsigned short)t;          lpsb[p] = (unsigned char)l0i; }
    if (l1i >= 0) { unsigned p = atomicAdd(&cur[l1i], 1u); ord[p] = (unsigned short)(t + 1024); lpsb[p] = (unsigned char)l1i; }
    __syncthreads();
    const int nt16 = (Tc + 15) >> 4;
    {
        const int padn = nt16 * 16 - Tc;              // 0..15
        if (Tc > 0 && t < padn) { ord[Tc + t] = ord[Tc - 1]; lpsb[Tc + t] = lpsb[Tc - 1]; }
    }
    __syncthreads();

    // ---- main: tiles of 16 sorted points, 3-deep pipelined gather ----
    float2 A0, A1, A2, A3, A4, B0, B1, B2, B3, B4, E0, E1, E2, E3, E4;
    const float2 fz = make_float2(0.f, 0.f);
    A0 = A1 = A2 = A3 = A4 = B0 = B1 = B2 = B3 = B4 = E0 = E1 = E2 = E3 = E4 = fz;

#define RECOF(TL) (((TL) < nt16) ? rec[base + (int)ord[(((TL)) << 4) + c0]] : 0u)
#define GATHERX(P0, P1, P2, P3, P4, RC) { \
        const float2* fp = (const float2*)(pts + (size_t)((RC) & 0x3FFFFFu) * C_IN); \
        if (g == 0)      { P0 = fp[0]; P1 = fp[1]; P2 = fp[2]; P3 = fp[3]; } \
        else if (g == 1) { P4 = fp[4]; } }

    int tile = w;
    {
        const unsigned r0 = RECOF(tile);
        const unsigned r1 = RECOF(tile + 16);
        const unsigned r2 = RECOF(tile + 32);
        if (tile      < nt16) GATHERX(A0, A1, A2, A3, A4, r0);
        if (tile + 16 < nt16) GATHERX(B0, B1, B2, B3, B4, r1);
        if (tile + 32 < nt16) GATHERX(E0, E1, E2, E3, E4, r2);
    }
    unsigned nrc = RECOF(tile + 48);

#define COMPUTE_AND_REFILL(P0, P1, P2, P3, P4) { \
        const int tb = tile << 4; \
        uint4 Aq; \
        if (g == 0)      Aq = make_uint4(pk2(P0), pk2(P1), pk2(P2), pk2(P3)); \
        else if (g == 1) Aq = make_uint4(pk2(P4), 0x00003F80u, 0u, 0u); \
        else             Aq = make_uint4(0u, 0u, 0u, 0u); \
        union { uint4 q; bf16x8 v; } Au; Au.q = Aq; \
        const unsigned L = *(const unsigned*)(lpsb + tb + (g << 2)); \
        /* refill this buffer for tile+48 while MFMA/reduce run */ \
        if (tile + 48 < nt16) GATHERX(P0, P1, P2, P3, P4, nrc); \
        nrc = RECOF(tile + 64); \
        const f32x4 z4 = {0.f, 0.f, 0.f, 0.f}; \
        f32x4 a0 = __builtin_amdgcn_mfma_f32_16x16x32_bf16(Au.v, bfrag[0], z4, 0, 0, 0); \
        f32x4 a1 = __builtin_amdgcn_mfma_f32_16x16x32_bf16(Au.v, bfrag[1], z4, 0, 0, 0); \
        f32x4 a2 = __builtin_amdgcn_mfma_f32_16x16x32_bf16(Au.v, bfrag[2], z4, 0, 0, 0); \
        f32x4 a3 = __builtin_amdgcn_mfma_f32_16x16x32_bf16(Au.v, bfrag[3], z4, 0, 0, 0); \
        const int lp0 = (int)(L & 255u), lp1 = (int)((L >> 8) & 255u), \
                  lp2 = (int)((L >> 16) & 255u), lp3 = (int)((L >> 24) & 255u); \
        float m0 = a0[0], m1 = a1[0], m2 = a2[0], m3 = a3[0]; \
        int cp = lp0; \
        if (lp1 == cp) { m0 = fmaxf(m0, a0[1]); m1 = fmaxf(m1, a1[1]); m2 = fmaxf(m2, a2[1]); m3 = fmaxf(m3, a3[1]); } \
        else { FLUSHM(); m0 = a0[1]; m1 = a1[1]; m2 = a2[1]; m3 = a3[1]; cp = lp1; } \
        if (lp2 == cp) { m0 = fmaxf(m0, a0[2]); m1 = fmaxf(m1, a1[2]); m2 = fmaxf(m2, a2[2]); m3 = fmaxf(m3, a3[2]); } \
        else { FLUSHM(); m0 = a0[2]; m1 = a1[2]; m2 = a2[2]; m3 = a3[2]; cp = lp2; } \
        if (lp3 == cp) { m0 = fmaxf(m0, a0[3]); m1 = fmaxf(m1, a1[3]); m2 = fmaxf(m2, a2[3]); m3 = fmaxf(m3, a3[3]); } \
        else { FLUSHM(); m0 = a0[3]; m1 = a1[3]; m2 = a2[3]; m3 = a3[3]; cp = lp3; } \
        FLUSHM(); \
        tile += 16; }

#define FLUSHM() { \
        unsigned* rowp = &smax[((unsigned)cp) << 6]; \
        const unsigned rb = (unsigned)(c0 + cp); \
        atomicMax(&rowp[(rb      ) & 63u], __float_as_uint(fmaxf(m0, 0.f))); \
        atomicMax(&rowp[(rb + 16u) & 63u], __float_as_uint(fmaxf(m1, 0.f))); \
        atomicMax(&rowp[(rb + 32u) & 63u], __float_as_uint(fmaxf(m2, 0.f))); \
        atomicMax(&rowp[(rb + 48u) & 63u], __float_as_uint(fmaxf(m3, 0.f))); }

    for (;;) {
        if (tile >= nt16) break;
        COMPUTE_AND_REFILL(A0, A1, A2, A3, A4);
        if (tile >= nt16) break;
        COMPUTE_AND_REFILL(B0, B1, B2, B3, B4);
        if (tile >= nt16) break;
        COMPUTE_AND_REFILL(E0, E1, E2, E3, E4);
    }
#undef COMPUTE_AND_REFILL
#undef FLUSHM
#undef GATHERX
#undef RECOF
    __syncthreads();

    // writeout: un-rotate by reading word (lane+row)&63; non-temporal stores
    for (int row = w; row < BPF; row += 16) {
        const int gp = b * BPF + row;
        if (gp < M) {
            const float v = __uint_as_float(smax[row * 64 + ((lane + row) & 63)]);
            __builtin_nontemporal_store(v, &out[(size_t)gp * C_OUT + lane]);
        }
    }

    // overflow (T > MAXT): cold path, practically never taken
    if (T > MAXT) {
        __syncthreads();
        for (int r = MAXT + w; r < T; r += 16) {
            const unsigned rc = rec[base + r];
            const float* fp = pts + (size_t)(rc & 0x3FFFFFu) * C_IN;
            float h = 0.f;
#pragma unroll
            for (int j = 0; j < C_IN; ++j) h = fmaf(fp[j], W[j * C_OUT + lane], h);
            const float sc = gamma[lane] * rsqrtf(var[lane] + BN_EPS);
            h = fmaxf(fmaf(h, sc, fmaf(-mean[lane], sc, beta[lane])), 0.f);
            const int gp = b * BPF + (int)(rc >> 22);
            atomicMax((unsigned*)&out[(size_t)gp * C_OUT + lane], __float_as_uint(h));
        }
    }
}

// ===========================================================================
// FALLBACK: global atomic scatter (round-0)
// ===========================================================================
__global__ __launch_bounds__(256) void zero_out_kernel(float4* __restrict__ out4, int n4) {
    int i = blockIdx.x * blockDim.x + threadIdx.x;
    int stride = gridDim.x * blockDim.x;
    float4 z = make_float4(0.f, 0.f, 0.f, 0.f);
    for (int j = i; j < n4; j += stride) out4[j] = z;
}

__global__ __launch_bounds__(256) void pillar_scatter_kernel(
    const float* __restrict__ pts, const int* __restrict__ idx,
    const float* __restrict__ W, const float* __restrict__ gamma,
    const float* __restrict__ beta, const float* __restrict__ mean,
    const float* __restrict__ var, unsigned int* __restrict__ out, int npoints)
{
    const int lane = threadIdx.x & 63;
    float wv[C_IN];
#pragma unroll
    for (int j = 0; j < C_IN; ++j) wv[j] = W[j * C_OUT + lane];
    const float scale = gamma[lane] * rsqrtf(var[lane] + BN_EPS);
    const float shift = fmaf(-mean[lane], scale, beta[lane]);
    const int wave_id = (blockIdx.x * blockDim.x + threadIdx.x) >> 6;
    const int nwaves  = (gridDim.x * blockDim.x) >> 6;
    for (int p = wave_id; p < npoints; p += nwaves) {
        const float* f = pts + (size_t)p * C_IN;
        float h = 0.f;
#pragma unroll
        for (int j = 0; j < C_IN; ++j) h = fmaf(f[j], wv[j], h);
        h = fmaxf(fmaf(h, scale, shift), 0.f);
        atomicMax(&out[(size_t)idx[p] * C_OUT + lane], __float_as_uint(h));
    }
}

// ===========================================================================

extern "C" void kernel_launch(void* const* d_in, const int* in_sizes, int n_in,
                              void* d_out, int out_size, void* d_ws, size_t ws_size,
                              hipStream_t stream) {
    const float* pts   = (const float*)d_in[0];
    const int*   idx   = (const int*)  d_in[1];
    const float* W     = (const float*)d_in[2];
    const float* gamma = (const float*)d_in[3];
    const float* beta  = (const float*)d_in[4];
    const float* mean  = (const float*)d_in[5];
    const float* var   = (const float*)d_in[6];

    const int npoints = in_sizes[0] / C_IN;     // 3,000,000
    const int M       = out_size / C_OUT;       // 600,000
    const int NB      = (M + BPF - 1) / BPF;    // 2344
    const int G       = NB * CB;                // 600K
    const int nt      = (G + TS - 1) / TS;      // 294
    const int chunk   = (npoints + CB - 1) / CB;

    // ws layout (u32): ghist[G] | tsum[nt] | bstart[NB+1] | pad | rec[n]
    const size_t head_u32 = (size_t)G + (size_t)nt + (size_t)NB + 1;
    const size_t head_b   = ((head_u32 * 4) + 63) & ~(size_t)63;
    const size_t need     = head_b + (size_t)npoints * 4;

    if (NB <= NBMAX && npoints < (1 << 22) && nt <= 65535 && ws_size >= need) {
        unsigned* ghist  = (unsigned*)d_ws;
        unsigned* tsum   = ghist + G;
        unsigned* bstart = tsum + nt;
        unsigned* rec    = (unsigned*)((char*)d_ws + head_b);

        k1_hist        <<<CB, 1024, 0, stream>>>(idx, npoints, chunk, ghist, NB, 8);
        k2a_reduce     <<<nt, 256,  0, stream>>>(ghist, G, tsum);
        k2b_scan       <<<1,  256,  0, stream>>>(tsum, nt);
        k2c_apply      <<<nt, 256,  0, stream>>>(ghist, G, tsum, bstart, NB, npoints);
        k3_scatter     <<<CB, 1024, 0, stream>>>(idx, npoints, chunk, ghist, rec, NB, 8, 255u);
        pool_sfm_kernel<<<NB, 1024, 0, stream>>>(pts, rec, bstart, W, gamma, beta,
                                                 mean, var, (float*)d_out, M);
        return;
    }

    // fallback: global atomics
    zero_out_kernel<<<2048, 256, 0, stream>>>((float4*)d_out, out_size / 4);
    pillar_scatter_kernel<<<2048, 256, 0, stream>>>(
        pts, idx, W, gamma, beta, mean, var, (unsigned int*)d_out, npoints);
}

// Round 13
// 227.698 us; speedup vs baseline: 1.4947x; 1.4947x over previous
//
#include <hip/hip_runtime.h>
#include <hip/hip_bf16.h>

#define C_IN 10
#define C_OUT 64
#define BN_EPS 1e-3f

#define BPF   256         // pillars per bucket (idx>>8)
#define CB    256         // chunk blocks for hist/scatter
#define NBMAX 4704        // LDS histogram capacity
#define TS    2048        // scan tile size
#define MAXT  2048        // in-LDS fine-sort capacity (lambda=1280, +21 sigma)

typedef __attribute__((ext_vector_type(8))) short bf16x8;
typedef __attribute__((ext_vector_type(4))) float f32x4;
typedef unsigned long long u64;

// ===========================================================================
// ATOMIC-FREE SORT PROLOGUE -> SELF-CONTAINED 24B bf16 RECORDS
// ws (u32): ghist[NB*CB] (scanned in place) | tsum[nt] | bstart[NB+1] | pad |
//           rec2[3n u64]  (record: w0,w1 = k0..3 | w2,w3 = k4..7 | w4 = k8,k9 | w5 = lp)
// ===========================================================================

__global__ __launch_bounds__(1024) void k1_hist(const int* __restrict__ idx, int n, int chunk,
                                                unsigned* __restrict__ ghist, int NB, int shift) {
    __shared__ unsigned h[NBMAX];
    const int b = blockIdx.x, t = threadIdx.x;
    for (int i = t; i < NB; i += 1024) h[i] = 0u;
    __syncthreads();
    const int lo = b * chunk;
    const int hi = min(n, lo + chunk);
    for (int i = lo + t; i < hi; i += 1024)
        atomicAdd(&h[((unsigned)idx[i]) >> shift], 1u);
    __syncthreads();
    for (int k = t; k < NB; k += 1024) ghist[(size_t)k * CB + b] = h[k];
}

__global__ __launch_bounds__(256) void k2a_reduce(const unsigned* __restrict__ g, int G,
                                                  unsigned* __restrict__ tsum) {
    __shared__ unsigned s[256];
    const int t = threadIdx.x;
    const int base = blockIdx.x * TS + t * 8;
    unsigned acc = 0;
#pragma unroll
    for (int j = 0; j < 8; ++j) { int gi = base + j; if (gi < G) acc += g[gi]; }
    s[t] = acc; __syncthreads();
    for (int off = 128; off > 0; off >>= 1) { if (t < off) s[t] += s[t + off]; __syncthreads(); }
    if (t == 0) tsum[blockIdx.x] = s[0];
}

__global__ __launch_bounds__(256) void k2b_scan(unsigned* __restrict__ tsum, int nt) {
    __shared__ unsigned partial[256], basev[256];
    const int t = threadIdx.x;
    const int per = (nt + 255) / 256;
    const int lo = t * per, hi = min(nt, lo + per);
    unsigned s = 0;
    for (int i = lo; i < hi; ++i) s += tsum[i];
    partial[t] = s; __syncthreads();
    if (t == 0) { unsigned a = 0; for (int k = 0; k < 256; ++k) { basev[k] = a; a += partial[k]; } }
    __syncthreads();
    unsigned a = basev[t];
    for (int i = lo; i < hi; ++i) { unsigned v = tsum[i]; tsum[i] = a; a += v; }
}

__global__ __launch_bounds__(256) void k2c_apply(unsigned* __restrict__ g, int G,
                                                 const unsigned* __restrict__ tsum,
                                                 unsigned* __restrict__ bstart, int NB, int n) {
    __shared__ unsigned s[256];
    const int t = threadIdx.x;
    const int base = blockIdx.x * TS + t * 8;
    unsigned v[8]; unsigned acc = 0;
#pragma unroll
    for (int j = 0; j < 8; ++j) { int gi = base + j; v[j] = (gi < G) ? g[gi] : 0u; acc += v[j]; }
    s[t] = acc; __syncthreads();
    for (int off = 1; off < 256; off <<= 1) {
        unsigned x = (t >= off) ? s[t - off] : 0u; __syncthreads();
        s[t] += x; __syncthreads();
    }
    unsigned excl = ((t == 0) ? 0u : s[t - 1]) + tsum[blockIdx.x];
#pragma unroll
    for (int j = 0; j < 8; ++j) {
        int gi = base + j;
        if (gi < G) {
            g[gi] = excl;
            if ((gi & (CB - 1)) == 0) bstart[gi / CB] = excl;
            excl += v[j];
        }
    }
    if (blockIdx.x == 0 && t == 0) bstart[NB] = (unsigned)n;
}

static __device__ __forceinline__ unsigned pk2(float2 v) {
    __hip_bfloat162 h = __float22bfloat162_rn(v);
    return *reinterpret_cast<unsigned*>(&h);
}

// K3b: sequential pts read (own chunk, coalesced) -> bf16 -> 24B record into
// bucket-sorted position. 1024 thr = 16 waves/CU for write-latency tolerance.
__global__ __launch_bounds__(1024) void k3b_scatter_feats(
    const int* __restrict__ idx, const float* __restrict__ pts, int n, int chunk,
    const unsigned* __restrict__ scanned, u64* __restrict__ rec2, int NB,
    int shift, unsigned lpmask)
{
    __shared__ unsigned cnt[NBMAX];
    __shared__ unsigned basel[NBMAX];
    const int b = blockIdx.x, t = threadIdx.x;
    for (int k = t; k < NB; k += 1024) { basel[k] = scanned[(size_t)k * CB + b]; cnt[k] = 0u; }
    __syncthreads();
    const int lo = b * chunk, hi = min(n, lo + chunk);
    for (int i = lo + t; i < hi; i += 1024) {
        const unsigned pid = (unsigned)idx[i];
        const float2* f2 = (const float2*)(pts + (size_t)i * C_IN);
        const float2 a0 = f2[0], a1 = f2[1], a2 = f2[2], a3 = f2[3], a4 = f2[4];
        const unsigned k = pid >> shift;
        const unsigned r = atomicAdd(&cnt[k], 1u);
        u64* o = rec2 + (size_t)(basel[k] + r) * 3;
        o[0] = (u64)pk2(a0) | ((u64)pk2(a1) << 32);
        o[1] = (u64)pk2(a2) | ((u64)pk2(a3) << 32);
        o[2] = (u64)pk2(a4) | ((u64)(pid & lpmask) << 32);
    }
}

// ===========================================================================
// K4 v9: record-fed fine-sorted MFMA pool. NO pts gather: each block streams
// its own ~30KB L2-resident record segment. A-frag = pure bit reassembly of
// the bf16 record (zero cvt). Only g<=1 lanes issue loads (384B/tile).
// Fine-sort + segmented pre-reduce + rotated smax: proven (R9/R10).
// ===========================================================================
__global__ __launch_bounds__(1024) void pool_rec2_kernel(
    const u64* __restrict__ rec2,
    const unsigned* __restrict__ bstart,
    const float* __restrict__ W,
    const float* __restrict__ gamma, const float* __restrict__ beta,
    const float* __restrict__ mean, const float* __restrict__ var,
    float* __restrict__ out, int M)
{
    __shared__ unsigned smax[BPF * C_OUT];            // 64 KB
    __shared__ unsigned short ord[MAXT + 16];         // 4.1 KB
    __shared__ unsigned lps32[(MAXT + 16) / 4];       // 2.1 KB
    __shared__ unsigned cnt[BPF];                     // 1 KB
    __shared__ unsigned cur[BPF];                     // 1 KB
    __shared__ unsigned wsum[4];
    unsigned char* lpsb = (unsigned char*)lps32;

    const int b = blockIdx.x, t = threadIdx.x;
    const int lane = t & 63, w = t >> 6;              // w in 0..15
    const int g = lane >> 4, c0 = lane & 15;

    {
        uint4* s4 = (uint4*)smax;
        const uint4 z = make_uint4(0u, 0u, 0u, 0u);
        for (int i = t; i < BPF * C_OUT / 4; i += 1024) s4[i] = z;
    }
    if (t < BPF) cnt[t] = 0u;

    // B' = W*diag(scale), row k=10 = shift (A k10 = 1.0), rows 11..31 = 0
    bf16x8 bfrag[4];
#pragma unroll
    for (int tc = 0; tc < 4; ++tc) {
        const int ch = 16 * tc + c0;
        const float sc = gamma[ch] * rsqrtf(var[ch] + BN_EPS);
        const float sh = fmaf(-mean[ch], sc, beta[ch]);
        union { bf16x8 v; unsigned short u[8]; } B;
#pragma unroll
        for (int j = 0; j < 8; ++j) {
            const int k = g * 8 + j;
            float val = 0.f;
            if (k < 10) val = W[k * C_OUT + ch] * sc;
            else if (k == 10) val = sh;
            __hip_bfloat16 hb = __float2bfloat16(val);
            B.u[j] = *reinterpret_cast<unsigned short*>(&hb);
        }
        bfrag[tc] = B.v;
    }

    const unsigned base = bstart[b];
    const int T  = (int)(bstart[b + 1] - base);
    const int Tc = T < MAXT ? T : MAXT;
    __syncthreads();

    // ---- fine sort by local pillar (lp = record word5) ----
    const unsigned* rec32 = (const unsigned*)rec2;
    int l0i = -1, l1i = -1;
    if (t < Tc)        { l0i = (int)(rec32[(size_t)(base + t) * 6 + 5] & 255u);        atomicAdd(&cnt[l0i], 1u); }
    if (t + 1024 < Tc) { l1i = (int)(rec32[(size_t)(base + t + 1024) * 6 + 5] & 255u); atomicAdd(&cnt[l1i], 1u); }
    __syncthreads();
    // exclusive scan of cnt[0..255] via 4-wave shfl scan (2 barriers)
    unsigned myv = 0, mys = 0;
    if (t < BPF) {
        myv = cnt[t];
        mys = myv;
#pragma unroll
        for (int off = 1; off < 64; off <<= 1) {
            unsigned y = (unsigned)__shfl_up((int)mys, off);
            if (lane >= off) mys += y;
        }
        if (lane == 63) wsum[t >> 6] = mys;
    }
    __syncthreads();
    if (t < BPF) {
        unsigned add = 0;
        const int mw = t >> 6;
        if (mw > 0) add += wsum[0];
        if (mw > 1) add += wsum[1];
        if (mw > 2) add += wsum[2];
        cur[t] = mys - myv + add;                     // exclusive scan
    }
    __syncthreads();
    if (l0i >= 0) { unsigned p = atomicAdd(&cur[l0i], 1u); ord[p] = (unsigned short)t;          lpsb[p] = (unsigned char)l0i; }
    if (l1i >= 0) { unsigned p = atomicAdd(&cur[l1i], 1u); ord[p] = (unsigned short)(t + 1024); lpsb[p] = (unsigned char)l1i; }
    __syncthreads();
    const int nt16 = (Tc + 15) >> 4;
    {
        const int padn = nt16 * 16 - Tc;              // 0..15
        if (Tc > 0 && t < padn) { ord[Tc + t] = ord[Tc - 1]; lpsb[Tc + t] = lpsb[Tc - 1]; }
    }
    __syncthreads();

    // ---- main: tiles of 16 sorted points; A-frag = record bits (no cvt) ----
    for (int tile = w; tile < nt16; tile += 16) {
        const int tb = tile << 4;
        const int o = (int)ord[tb + c0];
        const u64* r = rec2 + (size_t)(base + o) * 3;
        u64 q0 = 0, q1 = 0, q2 = 0;
        if (g == 0)      { q0 = r[0]; q1 = r[1]; }
        else if (g == 1) { q2 = r[2]; }

        uint4 Aq;
        if (g == 0)      Aq = make_uint4((unsigned)q0, (unsigned)(q0 >> 32),
                                         (unsigned)q1, (unsigned)(q1 >> 32));
        else if (g == 1) Aq = make_uint4((unsigned)q2, 0x00003F80u, 0u, 0u); // k8,k9 | k10=1.0
        else             Aq = make_uint4(0u, 0u, 0u, 0u);
        union { uint4 q; bf16x8 v; } A; A.q = Aq;

        const unsigned L = *(const unsigned*)(lpsb + tb + (g << 2));      // 4-aligned

        const f32x4 z4 = {0.f, 0.f, 0.f, 0.f};
        f32x4 a0 = __builtin_amdgcn_mfma_f32_16x16x32_bf16(A.v, bfrag[0], z4, 0, 0, 0);
        f32x4 a1 = __builtin_amdgcn_mfma_f32_16x16x32_bf16(A.v, bfrag[1], z4, 0, 0, 0);
        f32x4 a2 = __builtin_amdgcn_mfma_f32_16x16x32_bf16(A.v, bfrag[2], z4, 0, 0, 0);
        f32x4 a3 = __builtin_amdgcn_mfma_f32_16x16x32_bf16(A.v, bfrag[3], z4, 0, 0, 0);

        // segmented pre-reduce over this lane's 4 consecutive sorted rows
        const int lp0 = (int)(L & 255u), lp1 = (int)((L >> 8) & 255u),
                  lp2 = (int)((L >> 16) & 255u), lp3 = (int)((L >> 24) & 255u);
        float m0 = a0[0], m1 = a1[0], m2 = a2[0], m3 = a3[0];
        int cp = lp0;
#define FLUSHM() { \
        unsigned* rowp = &smax[((unsigned)cp) << 6]; \
        const unsigned rb = (unsigned)(c0 + cp); \
        atomicMax(&rowp[(rb      ) & 63u], __float_as_uint(fmaxf(m0, 0.f))); \
        atomicMax(&rowp[(rb + 16u) & 63u], __float_as_uint(fmaxf(m1, 0.f))); \
        atomicMax(&rowp[(rb + 32u) & 63u], __float_as_uint(fmaxf(m2, 0.f))); \
        atomicMax(&rowp[(rb + 48u) & 63u], __float_as_uint(fmaxf(m3, 0.f))); }
        if (lp1 == cp) { m0 = fmaxf(m0, a0[1]); m1 = fmaxf(m1, a1[1]); m2 = fmaxf(m2, a2[1]); m3 = fmaxf(m3, a3[1]); }
        else { FLUSHM(); m0 = a0[1]; m1 = a1[1]; m2 = a2[1]; m3 = a3[1]; cp = lp1; }
        if (lp2 == cp) { m0 = fmaxf(m0, a0[2]); m1 = fmaxf(m1, a1[2]); m2 = fmaxf(m2, a2[2]); m3 = fmaxf(m3, a3[2]); }
        else { FLUSHM(); m0 = a0[2]; m1 = a1[2]; m2 = a2[2]; m3 = a3[2]; cp = lp2; }
        if (lp3 == cp) { m0 = fmaxf(m0, a0[3]); m1 = fmaxf(m1, a1[3]); m2 = fmaxf(m2, a2[3]); m3 = fmaxf(m3, a3[3]); }
        else { FLUSHM(); m0 = a0[3]; m1 = a1[3]; m2 = a2[3]; m3 = a3[3]; cp = lp3; }
        FLUSHM();
#undef FLUSHM
    }
    __syncthreads();

    // writeout: un-rotate by reading word (lane+row)&63, coalesced 4B
    for (int row = w; row < BPF; row += 16) {
        const int gp = b * BPF + row;
        if (gp < M)
            out[(size_t)gp * C_OUT + lane] = __uint_as_float(smax[row * 64 + ((lane + row) & 63)]);
    }

    // overflow (T > MAXT): cold path, practically never taken
    if (T > MAXT) {
        __syncthreads();
        for (int r = MAXT + w; r < T; r += 16) {
            const u64* rp = rec2 + (size_t)(base + r) * 3;
            const u64 q0 = rp[0], q1 = rp[1], q2 = rp[2];
            unsigned fb[5] = { (unsigned)q0, (unsigned)(q0 >> 32),
                               (unsigned)q1, (unsigned)(q1 >> 32), (unsigned)q2 };
            float h = 0.f;
#pragma unroll
            for (int j = 0; j < 5; ++j) {
                const float flo = __uint_as_float((fb[j] & 0xFFFFu) << 16);
                const float fhi = __uint_as_float(fb[j] & 0xFFFF0000u);
                h = fmaf(flo, W[(2 * j) * C_OUT + lane], h);
                h = fmaf(fhi, W[(2 * j + 1) * C_OUT + lane], h);
            }
            const float sc = gamma[lane] * rsqrtf(var[lane] + BN_EPS);
            h = fmaxf(fmaf(h, sc, fmaf(-mean[lane], sc, beta[lane])), 0.f);
            const int gp = b * BPF + (int)((unsigned)(q2 >> 32) & 255u);
            atomicMax((unsigned*)&out[(size_t)gp * C_OUT + lane], __float_as_uint(h));
        }
    }
}

// ===========================================================================
// FALLBACK: global atomic scatter (round-0)
// ===========================================================================
__global__ __launch_bounds__(256) void zero_out_kernel(float4* __restrict__ out4, int n4) {
    int i = blockIdx.x * blockDim.x + threadIdx.x;
    int stride = gridDim.x * blockDim.x;
    float4 z = make_float4(0.f, 0.f, 0.f, 0.f);
    for (int j = i; j < n4; j += stride) out4[j] = z;
}

__global__ __launch_bounds__(256) void pillar_scatter_kernel(
    const float* __restrict__ pts, const int* __restrict__ idx,
    const float* __restrict__ W, const float* __restrict__ gamma,
    const float* __restrict__ beta, const float* __restrict__ mean,
    const float* __restrict__ var, unsigned int* __restrict__ out, int npoints)
{
    const int lane = threadIdx.x & 63;
    float wv[C_IN];
#pragma unroll
    for (int j = 0; j < C_IN; ++j) wv[j] = W[j * C_OUT + lane];
    const float scale = gamma[lane] * rsqrtf(var[lane] + BN_EPS);
    const float shift = fmaf(-mean[lane], scale, beta[lane]);
    const int wave_id = (blockIdx.x * blockDim.x + threadIdx.x) >> 6;
    const int nwaves  = (gridDim.x * blockDim.x) >> 6;
    for (int p = wave_id; p < npoints; p += nwaves) {
        const float* f = pts + (size_t)p * C_IN;
        float h = 0.f;
#pragma unroll
        for (int j = 0; j < C_IN; ++j) h = fmaf(f[j], wv[j], h);
        h = fmaxf(fmaf(h, scale, shift), 0.f);
        atomicMax(&out[(size_t)idx[p] * C_OUT + lane], __float_as_uint(h));
    }
}

// ===========================================================================

extern "C" void kernel_launch(void* const* d_in, const int* in_sizes, int n_in,
                              void* d_out, int out_size, void* d_ws, size_t ws_size,
                              hipStream_t stream) {
    const float* pts   = (const float*)d_in[0];
    const int*   idx   = (const int*)  d_in[1];
    const float* W     = (const float*)d_in[2];
    const float* gamma = (const float*)d_in[3];
    const float* beta  = (const float*)d_in[4];
    const float* mean  = (const float*)d_in[5];
    const float* var   = (const float*)d_in[6];

    const int npoints = in_sizes[0] / C_IN;     // 3,000,000
    const int M       = out_size / C_OUT;       // 600,000
    const int NB      = (M + BPF - 1) / BPF;    // 2344
    const int G       = NB * CB;                // 600K
    const int nt      = (G + TS - 1) / TS;      // 294
    const int chunk   = (npoints + CB - 1) / CB;

    // ws layout (u32 head): ghist[G] | tsum[nt] | bstart[NB+1] | pad | rec2[3n u64]
    const size_t head_u32 = (size_t)G + (size_t)nt + (size_t)NB + 1;
    const size_t head_b   = ((head_u32 * 4) + 63) & ~(size_t)63;
    const size_t need     = head_b + (size_t)npoints * 24;

    if (NB <= NBMAX && npoints < (1 << 22) && nt <= 65535 && ws_size >= need) {
        unsigned* ghist  = (unsigned*)d_ws;
        unsigned* tsum   = ghist + G;
        unsigned* bstart = tsum + nt;
        u64*      rec2   = (u64*)((char*)d_ws + head_b);

        k1_hist          <<<CB, 1024, 0, stream>>>(idx, npoints, chunk, ghist, NB, 8);
        k2a_reduce       <<<nt, 256,  0, stream>>>(ghist, G, tsum);
        k2b_scan         <<<1,  256,  0, stream>>>(tsum, nt);
        k2c_apply        <<<nt, 256,  0, stream>>>(ghist, G, tsum, bstart, NB, npoints);
        k3b_scatter_feats<<<CB, 1024, 0, stream>>>(idx, pts, npoints, chunk, ghist,
                                                   rec2, NB, 8, 255u);
        pool_rec2_kernel <<<NB, 1024, 0, stream>>>(rec2, bstart, W, gamma, beta,
                                                   mean, var, (float*)d_out, M);
        return;
    }

    // fallback: global atomics
    zero_out_kernel<<<2048, 256, 0, stream>>>((float4*)d_out, out_size / 4);
    pillar_scatter_kernel<<<2048, 256, 0, stream>>>(
        pts, idx, W, gamma, beta, mean, var, (unsigned int*)d_out, npoints);
}

// Round 14
// 224.985 us; speedup vs baseline: 1.5127x; 1.0121x over previous
//
#include <hip/hip_runtime.h>
#include <hip/hip_bf16.h>

#define C_IN 10
#define C_OUT 64
#define BN_EPS 1e-3f

#define BPF   256         // pillars per bucket (idx>>8)
#define CB    512         // chunk blocks for hist/scatter (2 blocks/CU)
#define NBMAX 4704        // LDS histogram capacity
#define TS    2048        // scan tile size
#define MAXT  2048        // in-LDS fine-sort capacity (lambda=1280, +21 sigma)

typedef __attribute__((ext_vector_type(8))) short bf16x8;
typedef __attribute__((ext_vector_type(4))) float f32x4;
typedef unsigned long long u64;

// ===========================================================================
// ATOMIC-FREE SORT PROLOGUE -> SELF-CONTAINED 24B bf16 RECORDS
// ws (u32): ghist[NB*CB] (scanned in place) | tsum[nt] | bstart[NB+1] | pad |
//           rec2[3n u64]  (record: w0,w1 = k0..3 | w2,w3 = k4..7 | w4 = k8,k9 | w5 = lp)
// ===========================================================================

__global__ __launch_bounds__(1024) void k1_hist(const int* __restrict__ idx, int n, int chunk,
                                                unsigned* __restrict__ ghist, int NB, int shift) {
    __shared__ unsigned h[NBMAX];
    const int b = blockIdx.x, t = threadIdx.x;
    for (int i = t; i < NB; i += 1024) h[i] = 0u;
    __syncthreads();
    const int lo = b * chunk;
    const int hi = min(n, lo + chunk);
    for (int i = lo + t; i < hi; i += 1024)
        atomicAdd(&h[((unsigned)idx[i]) >> shift], 1u);
    __syncthreads();
    for (int k = t; k < NB; k += 1024) ghist[(size_t)k * CB + b] = h[k];
}

__global__ __launch_bounds__(256) void k2a_reduce(const unsigned* __restrict__ g, int G,
                                                  unsigned* __restrict__ tsum) {
    __shared__ unsigned s[256];
    const int t = threadIdx.x;
    const int base = blockIdx.x * TS + t * 8;
    unsigned acc = 0;
#pragma unroll
    for (int j = 0; j < 8; ++j) { int gi = base + j; if (gi < G) acc += g[gi]; }
    s[t] = acc; __syncthreads();
    for (int off = 128; off > 0; off >>= 1) { if (t < off) s[t] += s[t + off]; __syncthreads(); }
    if (t == 0) tsum[blockIdx.x] = s[0];
}

__global__ __launch_bounds__(256) void k2b_scan(unsigned* __restrict__ tsum, int nt) {
    __shared__ unsigned partial[256], basev[256];
    const int t = threadIdx.x;
    const int per = (nt + 255) / 256;
    const int lo = t * per, hi = min(nt, lo + per);
    unsigned s = 0;
    for (int i = lo; i < hi; ++i) s += tsum[i];
    partial[t] = s; __syncthreads();
    if (t == 0) { unsigned a = 0; for (int k = 0; k < 256; ++k) { basev[k] = a; a += partial[k]; } }
    __syncthreads();
    unsigned a = basev[t];
    for (int i = lo; i < hi; ++i) { unsigned v = tsum[i]; tsum[i] = a; a += v; }
}

__global__ __launch_bounds__(256) void k2c_apply(unsigned* __restrict__ g, int G,
                                                 const unsigned* __restrict__ tsum,
                                                 unsigned* __restrict__ bstart, int NB, int n) {
    __shared__ unsigned s[256];
    const int t = threadIdx.x;
    const int base = blockIdx.x * TS + t * 8;
    unsigned v[8]; unsigned acc = 0;
#pragma unroll
    for (int j = 0; j < 8; ++j) { int gi = base + j; v[j] = (gi < G) ? g[gi] : 0u; acc += v[j]; }
    s[t] = acc; __syncthreads();
    for (int off = 1; off < 256; off <<= 1) {
        unsigned x = (t >= off) ? s[t - off] : 0u; __syncthreads();
        s[t] += x; __syncthreads();
    }
    unsigned excl = ((t == 0) ? 0u : s[t - 1]) + tsum[blockIdx.x];
#pragma unroll
    for (int j = 0; j < 8; ++j) {
        int gi = base + j;
        if (gi < G) {
            g[gi] = excl;
            if ((gi & (CB - 1)) == 0) bstart[gi / CB] = excl;
            excl += v[j];
        }
    }
    if (blockIdx.x == 0 && t == 0) bstart[NB] = (unsigned)n;
}

static __device__ __forceinline__ unsigned pk2(float2 v) {
    __hip_bfloat162 h = __float22bfloat162_rn(v);
    return *reinterpret_cast<unsigned*>(&h);
}

// K3b: sequential pts read -> bf16 -> 24B record into bucket-sorted position.
// Merged base+counter LDS array (18.9 KB -> 2 blocks/CU); 2-way unrolled for MLP.
__global__ __launch_bounds__(1024) void k3b_scatter_feats(
    const int* __restrict__ idx, const float* __restrict__ pts, int n, int chunk,
    const unsigned* __restrict__ scanned, u64* __restrict__ rec2, int NB,
    int shift, unsigned lpmask)
{
    __shared__ unsigned cnt[NBMAX];                   // absolute cursor per bucket
    const int b = blockIdx.x, t = threadIdx.x;
    for (int k = t; k < NB; k += 1024) cnt[k] = scanned[(size_t)k * CB + b];
    __syncthreads();
    const int lo = b * chunk, hi = min(n, lo + chunk);

    int i = lo + t;
    for (; i + 1024 < hi; i += 2048) {
        // two independent chains in flight
        const unsigned pa = (unsigned)idx[i];
        const unsigned pb = (unsigned)idx[i + 1024];
        const float2* fa = (const float2*)(pts + (size_t)i * C_IN);
        const float2* fb = (const float2*)(pts + (size_t)(i + 1024) * C_IN);
        const float2 a0 = fa[0], a1 = fa[1], a2 = fa[2], a3 = fa[3], a4 = fa[4];
        const float2 b0 = fb[0], b1 = fb[1], b2 = fb[2], b3 = fb[3], b4 = fb[4];
        const unsigned ra = atomicAdd(&cnt[pa >> shift], 1u);
        const unsigned rb = atomicAdd(&cnt[pb >> shift], 1u);
        u64* oa = rec2 + (size_t)ra * 3;
        u64* ob = rec2 + (size_t)rb * 3;
        oa[0] = (u64)pk2(a0) | ((u64)pk2(a1) << 32);
        oa[1] = (u64)pk2(a2) | ((u64)pk2(a3) << 32);
        oa[2] = (u64)pk2(a4) | ((u64)(pa & lpmask) << 32);
        ob[0] = (u64)pk2(b0) | ((u64)pk2(b1) << 32);
        ob[1] = (u64)pk2(b2) | ((u64)pk2(b3) << 32);
        ob[2] = (u64)pk2(b4) | ((u64)(pb & lpmask) << 32);
    }
    if (i < hi) {
        const unsigned pa = (unsigned)idx[i];
        const float2* fa = (const float2*)(pts + (size_t)i * C_IN);
        const float2 a0 = fa[0], a1 = fa[1], a2 = fa[2], a3 = fa[3], a4 = fa[4];
        const unsigned ra = atomicAdd(&cnt[pa >> shift], 1u);
        u64* oa = rec2 + (size_t)ra * 3;
        oa[0] = (u64)pk2(a0) | ((u64)pk2(a1) << 32);
        oa[1] = (u64)pk2(a2) | ((u64)pk2(a3) << 32);
        oa[2] = (u64)pk2(a4) | ((u64)(pa & lpmask) << 32);
    }
}

// ===========================================================================
// K4 v9 (unchanged from R12 — proven): record-fed fine-sorted MFMA pool.
// ===========================================================================
__global__ __launch_bounds__(1024) void pool_rec2_kernel(
    const u64* __restrict__ rec2,
    const unsigned* __restrict__ bstart,
    const float* __restrict__ W,
    const float* __restrict__ gamma, const float* __restrict__ beta,
    const float* __restrict__ mean, const float* __restrict__ var,
    float* __restrict__ out, int M)
{
    __shared__ unsigned smax[BPF * C_OUT];            // 64 KB
    __shared__ unsigned short ord[MAXT + 16];         // 4.1 KB
    __shared__ unsigned lps32[(MAXT + 16) / 4];       // 2.1 KB
    __shared__ unsigned cnt[BPF];                     // 1 KB
    __shared__ unsigned cur[BPF];                     // 1 KB
    __shared__ unsigned wsum[4];
    unsigned char* lpsb = (unsigned char*)lps32;

    const int b = blockIdx.x, t = threadIdx.x;
    const int lane = t & 63, w = t >> 6;              // w in 0..15
    const int g = lane >> 4, c0 = lane & 15;

    {
        uint4* s4 = (uint4*)smax;
        const uint4 z = make_uint4(0u, 0u, 0u, 0u);
        for (int i = t; i < BPF * C_OUT / 4; i += 1024) s4[i] = z;
    }
    if (t < BPF) cnt[t] = 0u;

    // B' = W*diag(scale), row k=10 = shift (A k10 = 1.0), rows 11..31 = 0
    bf16x8 bfrag[4];
#pragma unroll
    for (int tc = 0; tc < 4; ++tc) {
        const int ch = 16 * tc + c0;
        const float sc = gamma[ch] * rsqrtf(var[ch] + BN_EPS);
        const float sh = fmaf(-mean[ch], sc, beta[ch]);
        union { bf16x8 v; unsigned short u[8]; } B;
#pragma unroll
        for (int j = 0; j < 8; ++j) {
            const int k = g * 8 + j;
            float val = 0.f;
            if (k < 10) val = W[k * C_OUT + ch] * sc;
            else if (k == 10) val = sh;
            __hip_bfloat16 hb = __float2bfloat16(val);
            B.u[j] = *reinterpret_cast<unsigned short*>(&hb);
        }
        bfrag[tc] = B.v;
    }

    const unsigned base = bstart[b];
    const int T  = (int)(bstart[b + 1] - base);
    const int Tc = T < MAXT ? T : MAXT;
    __syncthreads();

    // ---- fine sort by local pillar (lp = record word5) ----
    const unsigned* rec32 = (const unsigned*)rec2;
    int l0i = -1, l1i = -1;
    if (t < Tc)        { l0i = (int)(rec32[(size_t)(base + t) * 6 + 5] & 255u);        atomicAdd(&cnt[l0i], 1u); }
    if (t + 1024 < Tc) { l1i = (int)(rec32[(size_t)(base + t + 1024) * 6 + 5] & 255u); atomicAdd(&cnt[l1i], 1u); }
    __syncthreads();
    // exclusive scan of cnt[0..255] via 4-wave shfl scan (2 barriers)
    unsigned myv = 0, mys = 0;
    if (t < BPF) {
        myv = cnt[t];
        mys = myv;
#pragma unroll
        for (int off = 1; off < 64; off <<= 1) {
            unsigned y = (unsigned)__shfl_up((int)mys, off);
            if (lane >= off) mys += y;
        }
        if (lane == 63) wsum[t >> 6] = mys;
    }
    __syncthreads();
    if (t < BPF) {
        unsigned add = 0;
        const int mw = t >> 6;
        if (mw > 0) add += wsum[0];
        if (mw > 1) add += wsum[1];
        if (mw > 2) add += wsum[2];
        cur[t] = mys - myv + add;                     // exclusive scan
    }
    __syncthreads();
    if (l0i >= 0) { unsigned p = atomicAdd(&cur[l0i], 1u); ord[p] = (unsigned short)t;          lpsb[p] = (unsigned char)l0i; }
    if (l1i >= 0) { unsigned p = atomicAdd(&cur[l1i], 1u); ord[p] = (unsigned short)(t + 1024); lpsb[p] = (unsigned char)l1i; }
    __syncthreads();
    const int nt16 = (Tc + 15) >> 4;
    {
        const int padn = nt16 * 16 - Tc;              // 0..15
        if (Tc > 0 && t < padn) { ord[Tc + t] = ord[Tc - 1]; lpsb[Tc + t] = lpsb[Tc - 1]; }
    }
    __syncthreads();

    // ---- main: tiles of 16 sorted points; A-frag = record bits (no cvt) ----
    for (int tile = w; tile < nt16; tile += 16) {
        const int tb = tile << 4;
        const int o = (int)ord[tb + c0];
        const u64* r = rec2 + (size_t)(base + o) * 3;
        u64 q0 = 0, q1 = 0, q2 = 0;
        if (g == 0)      { q0 = r[0]; q1 = r[1]; }
        else if (g == 1) { q2 = r[2]; }

        uint4 Aq;
        if (g == 0)      Aq = make_uint4((unsigned)q0, (unsigned)(q0 >> 32),
                                         (unsigned)q1, (unsigned)(q1 >> 32));
        else if (g == 1) Aq = make_uint4((unsigned)q2, 0x00003F80u, 0u, 0u); // k8,k9 | k10=1.0
        else             Aq = make_uint4(0u, 0u, 0u, 0u);
        union { uint4 q; bf16x8 v; } A; A.q = Aq;

        const unsigned L = *(const unsigned*)(lpsb + tb + (g << 2));      // 4-aligned

        const f32x4 z4 = {0.f, 0.f, 0.f, 0.f};
        f32x4 a0 = __builtin_amdgcn_mfma_f32_16x16x32_bf16(A.v, bfrag[0], z4, 0, 0, 0);
        f32x4 a1 = __builtin_amdgcn_mfma_f32_16x16x32_bf16(A.v, bfrag[1], z4, 0, 0, 0);
        f32x4 a2 = __builtin_amdgcn_mfma_f32_16x16x32_bf16(A.v, bfrag[2], z4, 0, 0, 0);
        f32x4 a3 = __builtin_amdgcn_mfma_f32_16x16x32_bf16(A.v, bfrag[3], z4, 0, 0, 0);

        // segmented pre-reduce over this lane's 4 consecutive sorted rows
        const int lp0 = (int)(L & 255u), lp1 = (int)((L >> 8) & 255u),
                  lp2 = (int)((L >> 16) & 255u), lp3 = (int)((L >> 24) & 255u);
        float m0 = a0[0], m1 = a1[0], m2 = a2[0], m3 = a3[0];
        int cp = lp0;
#define FLUSHM() { \
        unsigned* rowp = &smax[((unsigned)cp) << 6]; \
        const unsigned rb = (unsigned)(c0 + cp); \
        atomicMax(&rowp[(rb      ) & 63u], __float_as_uint(fmaxf(m0, 0.f))); \
        atomicMax(&rowp[(rb + 16u) & 63u], __float_as_uint(fmaxf(m1, 0.f))); \
        atomicMax(&rowp[(rb + 32u) & 63u], __float_as_uint(fmaxf(m2, 0.f))); \
        atomicMax(&rowp[(rb + 48u) & 63u], __float_as_uint(fmaxf(m3, 0.f))); }
        if (lp1 == cp) { m0 = fmaxf(m0, a0[1]); m1 = fmaxf(m1, a1[1]); m2 = fmaxf(m2, a2[1]); m3 = fmaxf(m3, a3[1]); }
        else { FLUSHM(); m0 = a0[1]; m1 = a1[1]; m2 = a2[1]; m3 = a3[1]; cp = lp1; }
        if (lp2 == cp) { m0 = fmaxf(m0, a0[2]); m1 = fmaxf(m1, a1[2]); m2 = fmaxf(m2, a2[2]); m3 = fmaxf(m3, a3[2]); }
        else { FLUSHM(); m0 = a0[2]; m1 = a1[2]; m2 = a2[2]; m3 = a3[2]; cp = lp2; }
        if (lp3 == cp) { m0 = fmaxf(m0, a0[3]); m1 = fmaxf(m1, a1[3]); m2 = fmaxf(m2, a2[3]); m3 = fmaxf(m3, a3[3]); }
        else { FLUSHM(); m0 = a0[3]; m1 = a1[3]; m2 = a2[3]; m3 = a3[3]; cp = lp3; }
        FLUSHM();
#undef FLUSHM
    }
    __syncthreads();

    // writeout: un-rotate by reading word (lane+row)&63, coalesced 4B
    for (int row = w; row < BPF; row += 16) {
        const int gp = b * BPF + row;
        if (gp < M)
            out[(size_t)gp * C_OUT + lane] = __uint_as_float(smax[row * 64 + ((lane + row) & 63)]);
    }

    // overflow (T > MAXT): cold path, practically never taken
    if (T > MAXT) {
        __syncthreads();
        for (int r = MAXT + w; r < T; r += 16) {
            const u64* rp = rec2 + (size_t)(base + r) * 3;
            const u64 q0 = rp[0], q1 = rp[1], q2 = rp[2];
            unsigned fb[5] = { (unsigned)q0, (unsigned)(q0 >> 32),
                               (unsigned)q1, (unsigned)(q1 >> 32), (unsigned)q2 };
            float h = 0.f;
#pragma unroll
            for (int j = 0; j < 5; ++j) {
                const float flo = __uint_as_float((fb[j] & 0xFFFFu) << 16);
                const float fhi = __uint_as_float(fb[j] & 0xFFFF0000u);
                h = fmaf(flo, W[(2 * j) * C_OUT + lane], h);
                h = fmaf(fhi, W[(2 * j + 1) * C_OUT + lane], h);
            }
            const float sc = gamma[lane] * rsqrtf(var[lane] + BN_EPS);
            h = fmaxf(fmaf(h, sc, fmaf(-mean[lane], sc, beta[lane])), 0.f);
            const int gp = b * BPF + (int)((unsigned)(q2 >> 32) & 255u);
            atomicMax((unsigned*)&out[(size_t)gp * C_OUT + lane], __float_as_uint(h));
        }
    }
}

// ===========================================================================
// FALLBACK: global atomic scatter (round-0)
// ===========================================================================
__global__ __launch_bounds__(256) void zero_out_kernel(float4* __restrict__ out4, int n4) {
    int i = blockIdx.x * blockDim.x + threadIdx.x;
    int stride = gridDim.x * blockDim.x;
    float4 z = make_float4(0.f, 0.f, 0.f, 0.f);
    for (int j = i; j < n4; j += stride) out4[j] = z;
}

__global__ __launch_bounds__(256) void pillar_scatter_kernel(
    const float* __restrict__ pts, const int* __restrict__ idx,
    const float* __restrict__ W, const float* __restrict__ gamma,
    const float* __restrict__ beta, const float* __restrict__ mean,
    const float* __restrict__ var, unsigned int* __restrict__ out, int npoints)
{
    const int lane = threadIdx.x & 63;
    float wv[C_IN];
#pragma unroll
    for (int j = 0; j < C_IN; ++j) wv[j] = W[j * C_OUT + lane];
    const float scale = gamma[lane] * rsqrtf(var[lane] + BN_EPS);
    const float shift = fmaf(-mean[lane], scale, beta[lane]);
    const int wave_id = (blockIdx.x * blockDim.x + threadIdx.x) >> 6;
    const int nwaves  = (gridDim.x * blockDim.x) >> 6;
    for (int p = wave_id; p < npoints; p += nwaves) {
        const float* f = pts + (size_t)p * C_IN;
        float h = 0.f;
#pragma unroll
        for (int j = 0; j < C_IN; ++j) h = fmaf(f[j], wv[j], h);
        h = fmaxf(fmaf(h, scale, shift), 0.f);
        atomicMax(&out[(size_t)idx[p] * C_OUT + lane], __float_as_uint(h));
    }
}

// ===========================================================================

extern "C" void kernel_launch(void* const* d_in, const int* in_sizes, int n_in,
                              void* d_out, int out_size, void* d_ws, size_t ws_size,
                              hipStream_t stream) {
    const float* pts   = (const float*)d_in[0];
    const int*   idx   = (const int*)  d_in[1];
    const float* W     = (const float*)d_in[2];
    const float* gamma = (const float*)d_in[3];
    const float* beta  = (const float*)d_in[4];
    const float* mean  = (const float*)d_in[5];
    const float* var   = (const float*)d_in[6];

    const int npoints = in_sizes[0] / C_IN;     // 3,000,000
    const int M       = out_size / C_OUT;       // 600,000
    const int NB      = (M + BPF - 1) / BPF;    // 2344
    const int G       = NB * CB;                // 1.2M
    const int nt      = (G + TS - 1) / TS;      // 586
    const int chunk   = (npoints + CB - 1) / CB;

    // ws layout (u32 head): ghist[G] | tsum[nt] | bstart[NB+1] | pad | rec2[3n u64]
    const size_t head_u32 = (size_t)G + (size_t)nt + (size_t)NB + 1;
    const size_t head_b   = ((head_u32 * 4) + 63) & ~(size_t)63;
    const size_t need     = head_b + (size_t)npoints * 24;

    if (NB <= NBMAX && npoints < (1 << 22) && nt <= 65535 && ws_size >= need) {
        unsigned* ghist  = (unsigned*)d_ws;
        unsigned* tsum   = ghist + G;
        unsigned* bstart = tsum + nt;
        u64*      rec2   = (u64*)((char*)d_ws + head_b);

        k1_hist          <<<CB, 1024, 0, stream>>>(idx, npoints, chunk, ghist, NB, 8);
        k2a_reduce       <<<nt, 256,  0, stream>>>(ghist, G, tsum);
        k2b_scan         <<<1,  256,  0, stream>>>(tsum, nt);
        k2c_apply        <<<nt, 256,  0, stream>>>(ghist, G, tsum, bstart, NB, npoints);
        k3b_scatter_feats<<<CB, 1024, 0, stream>>>(idx, pts, npoints, chunk, ghist,
                                                   rec2, NB, 8, 255u);
        pool_rec2_kernel <<<NB, 1024, 0, stream>>>(rec2, bstart, W, gamma, beta,
                                                   mean, var, (float*)d_out, M);
        return;
    }

    // fallback: global atomics
    zero_out_kernel<<<2048, 256, 0, stream>>>((float4*)d_out, out_size / 4);
    pillar_scatter_kernel<<<2048, 256, 0, stream>>>(
        pts, idx, W, gamma, beta, mean, var, (unsigned int*)d_out, npoints);
}

// Round 15
// 198.324 us; speedup vs baseline: 1.7160x; 1.1344x over previous
//
#include <hip/hip_runtime.h>
#include <hip/hip_bf16.h>

#define C_IN 10
#define C_OUT 64
#define BN_EPS 1e-3f

#define BPF   256         // pillars per bucket (idx>>8)
#define CB    256         // chunk blocks for hist/scatter
#define NBMAX 4704        // LDS histogram capacity
#define TS    2048        // scan tile size
#define MAXT  2048        // in-LDS fine-sort capacity (lambda=1280, +21 sigma)

typedef __attribute__((ext_vector_type(8))) short bf16x8;
typedef __attribute__((ext_vector_type(4))) float f32x4;

// ===========================================================================
// ATOMIC-FREE SORT PROLOGUE (4B records: lp<<22 | pointIdx)  — proven, ~35us
// ws (u32): ghist[NB*CB] (scanned in place) | tsum[nt] | bstart[NB+1] | rec[n]
// ===========================================================================

__global__ __launch_bounds__(1024) void k1_hist(const int* __restrict__ idx, int n, int chunk,
                                                unsigned* __restrict__ ghist, int NB, int shift) {
    __shared__ unsigned h[NBMAX];
    const int b = blockIdx.x, t = threadIdx.x;
    for (int i = t; i < NB; i += 1024) h[i] = 0u;
    __syncthreads();
    const int lo = b * chunk;
    const int hi = min(n, lo + chunk);
    for (int i = lo + t; i < hi; i += 1024)
        atomicAdd(&h[((unsigned)idx[i]) >> shift], 1u);
    __syncthreads();
    for (int k = t; k < NB; k += 1024) ghist[(size_t)k * CB + b] = h[k];
}

__global__ __launch_bounds__(256) void k2a_reduce(const unsigned* __restrict__ g, int G,
                                                  unsigned* __restrict__ tsum) {
    __shared__ unsigned s[256];
    const int t = threadIdx.x;
    const int base = blockIdx.x * TS + t * 8;
    unsigned acc = 0;
#pragma unroll
    for (int j = 0; j < 8; ++j) { int gi = base + j; if (gi < G) acc += g[gi]; }
    s[t] = acc; __syncthreads();
    for (int off = 128; off > 0; off >>= 1) { if (t < off) s[t] += s[t + off]; __syncthreads(); }
    if (t == 0) tsum[blockIdx.x] = s[0];
}

__global__ __launch_bounds__(256) void k2b_scan(unsigned* __restrict__ tsum, int nt) {
    __shared__ unsigned partial[256], basev[256];
    const int t = threadIdx.x;
    const int per = (nt + 255) / 256;
    const int lo = t * per, hi = min(nt, lo + per);
    unsigned s = 0;
    for (int i = lo; i < hi; ++i) s += tsum[i];
    partial[t] = s; __syncthreads();
    if (t == 0) { unsigned a = 0; for (int k = 0; k < 256; ++k) { basev[k] = a; a += partial[k]; } }
    __syncthreads();
    unsigned a = basev[t];
    for (int i = lo; i < hi; ++i) { unsigned v = tsum[i]; tsum[i] = a; a += v; }
}

__global__ __launch_bounds__(256) void k2c_apply(unsigned* __restrict__ g, int G,
                                                 const unsigned* __restrict__ tsum,
                                                 unsigned* __restrict__ bstart, int NB, int n) {
    __shared__ unsigned s[256];
    const int t = threadIdx.x;
    const int base = blockIdx.x * TS + t * 8;
    unsigned v[8]; unsigned acc = 0;
#pragma unroll
    for (int j = 0; j < 8; ++j) { int gi = base + j; v[j] = (gi < G) ? g[gi] : 0u; acc += v[j]; }
    s[t] = acc; __syncthreads();
    for (int off = 1; off < 256; off <<= 1) {
        unsigned x = (t >= off) ? s[t - off] : 0u; __syncthreads();
        s[t] += x; __syncthreads();
    }
    unsigned excl = ((t == 0) ? 0u : s[t - 1]) + tsum[blockIdx.x];
#pragma unroll
    for (int j = 0; j < 8; ++j) {
        int gi = base + j;
        if (gi < G) {
            g[gi] = excl;
            if ((gi & (CB - 1)) == 0) bstart[gi / CB] = excl;
            excl += v[j];
        }
    }
    if (blockIdx.x == 0 && t == 0) bstart[NB] = (unsigned)n;
}

__global__ __launch_bounds__(1024) void k3_scatter(const int* __restrict__ idx, int n, int chunk,
                                                   const unsigned* __restrict__ scanned,
                                                   unsigned* __restrict__ rec, int NB,
                                                   int shift, unsigned lpmask) {
    __shared__ unsigned cnt[NBMAX];
    __shared__ unsigned basel[NBMAX];
    const int b = blockIdx.x, t = threadIdx.x;
    for (int k = t; k < NB; k += 1024) { basel[k] = scanned[(size_t)k * CB + b]; cnt[k] = 0u; }
    __syncthreads();
    const int lo = b * chunk, hi = min(n, lo + chunk);
    for (int i = lo + t; i < hi; i += 1024) {
        unsigned pid = (unsigned)idx[i];
        unsigned k = pid >> shift;
        unsigned r = atomicAdd(&cnt[k], 1u);
        rec[basel[k] + r] = ((pid & lpmask) << 22) | (unsigned)i;
    }
}

static __device__ __forceinline__ unsigned pk2(float2 v) {
    __hip_bfloat162 h = __float22bfloat162_rn(v);
    return *reinterpret_cast<unsigned*>(&h);
}

// ===========================================================================
// K4 (R10 champion): fine-sorted MFMA pool with 2-deep pipelined gather.
//   pipeline per wave: [tile+32] ord->rec (LDS+L1)  ||  [tile+16] pts gather
//   (HBM, using previously staged rc)  ||  [tile] pack+MFMA+segmented reduce.
//   Fine-sort scan = 4-wave __shfl_up (2 barriers).
//   Single change vs R10: non-temporal stores on the output writeout.
// ===========================================================================
__global__ __launch_bounds__(1024) void pool_sfm_kernel(
    const float* __restrict__ pts,
    const unsigned* __restrict__ rec,
    const unsigned* __restrict__ bstart,
    const float* __restrict__ W,
    const float* __restrict__ gamma, const float* __restrict__ beta,
    const float* __restrict__ mean, const float* __restrict__ var,
    float* __restrict__ out, int M)
{
    __shared__ unsigned smax[BPF * C_OUT];            // 64 KB
    __shared__ unsigned short ord[MAXT + 16];         // 4.1 KB
    __shared__ unsigned lps32[(MAXT + 16) / 4];       // 2.1 KB
    __shared__ unsigned cnt[BPF];                     // 1 KB
    __shared__ unsigned cur[BPF];                     // 1 KB
    __shared__ unsigned wsum[4];
    unsigned char* lpsb = (unsigned char*)lps32;

    const int b = blockIdx.x, t = threadIdx.x;
    const int lane = t & 63, w = t >> 6;              // w in 0..15
    const int g = lane >> 4, c0 = lane & 15;

    {
        uint4* s4 = (uint4*)smax;
        const uint4 z = make_uint4(0u, 0u, 0u, 0u);
        for (int i = t; i < BPF * C_OUT / 4; i += 1024) s4[i] = z;
    }
    if (t < BPF) cnt[t] = 0u;

    // B' = W*diag(scale), row k=10 = shift (A k10 = 1.0), rows 11..31 = 0
    bf16x8 bfrag[4];
#pragma unroll
    for (int tc = 0; tc < 4; ++tc) {
        const int ch = 16 * tc + c0;
        const float sc = gamma[ch] * rsqrtf(var[ch] + BN_EPS);
        const float sh = fmaf(-mean[ch], sc, beta[ch]);
        union { bf16x8 v; unsigned short u[8]; } B;
#pragma unroll
        for (int j = 0; j < 8; ++j) {
            const int k = g * 8 + j;
            float val = 0.f;
            if (k < 10) val = W[k * C_OUT + ch] * sc;
            else if (k == 10) val = sh;
            __hip_bfloat16 hb = __float2bfloat16(val);
            B.u[j] = *reinterpret_cast<unsigned short*>(&hb);
        }
        bfrag[tc] = B.v;
    }

    const unsigned base = bstart[b];
    const int T  = (int)(bstart[b + 1] - base);
    const int Tc = T < MAXT ? T : MAXT;
    __syncthreads();

    // ---- fine sort by local pillar ----
    int l0i = -1, l1i = -1;
    if (t < Tc)        { l0i = (int)(rec[base + t] >> 22);        atomicAdd(&cnt[l0i], 1u); }
    if (t + 1024 < Tc) { l1i = (int)(rec[base + t + 1024] >> 22); atomicAdd(&cnt[l1i], 1u); }
    __syncthreads();
    // exclusive scan of cnt[0..255] via 4-wave shfl scan (2 barriers)
    unsigned myv = 0, mys = 0;
    if (t < BPF) {
        myv = cnt[t];
        mys = myv;
#pragma unroll
        for (int off = 1; off < 64; off <<= 1) {
            unsigned y = (unsigned)__shfl_up((int)mys, off);
            if (lane >= off) mys += y;
        }
        if (lane == 63) wsum[t >> 6] = mys;
    }
    __syncthreads();
    if (t < BPF) {
        unsigned add = 0;
        const int mw = t >> 6;
        if (mw > 0) add += wsum[0];
        if (mw > 1) add += wsum[1];
        if (mw > 2) add += wsum[2];
        cur[t] = mys - myv + add;                     // exclusive scan
    }
    __syncthreads();
    if (l0i >= 0) { unsigned p = atomicAdd(&cur[l0i], 1u); ord[p] = (unsigned short)t;          lpsb[p] = (unsigned char)l0i; }
    if (l1i >= 0) { unsigned p = atomicAdd(&cur[l1i], 1u); ord[p] = (unsigned short)(t + 1024); lpsb[p] = (unsigned char)l1i; }
    __syncthreads();
    const int nt16 = (Tc + 15) >> 4;
    {
        const int padn = nt16 * 16 - Tc;              // 0..15
        if (Tc > 0 && t < padn) { ord[Tc + t] = ord[Tc - 1]; lpsb[Tc + t] = lpsb[Tc - 1]; }
    }
    __syncthreads();

    // ---- main: tiles of 16 sorted points, 2-deep pipelined gather ----
    int tile = w;
    unsigned rcB = 0u;                                 // rec for tile+16
    float2 x0p, x1p, x2p, x3p, x4p;                    // pts data for current tile
    x0p = x1p = x2p = x3p = x4p = make_float2(0.f, 0.f);
    if (tile < nt16) {
        const int o = (int)ord[(tile << 4) + c0];
        const unsigned rcA = rec[base + o];
        const float2* fp = (const float2*)(pts + (size_t)(rcA & 0x3FFFFFu) * C_IN);
        if (g == 0)      { x0p = fp[0]; x1p = fp[1]; x2p = fp[2]; x3p = fp[3]; }
        else if (g == 1) { x4p = fp[4]; }
    }
    if (tile + 16 < nt16) {
        const int o = (int)ord[((tile + 16) << 4) + c0];
        rcB = rec[base + o];
    }

    for (; tile < nt16; tile += 16) {
        const int tb = tile << 4;
        // capture current tile's data
        const float2 x0 = x0p, x1 = x1p, x2 = x2p, x3 = x3p, x4 = x4p;

        // stage A: rec address for tile+32 (LDS + L1-hot)
        unsigned rcC = 0u;
        if (tile + 32 < nt16) {
            const int o = (int)ord[((tile + 32) << 4) + c0];
            rcC = rec[base + o];
        }
        // stage B: pts gather for tile+16 (HBM; latency hides under compute)
        if (tile + 16 < nt16) {
            const float2* fp = (const float2*)(pts + (size_t)(rcB & 0x3FFFFFu) * C_IN);
            if (g == 0)      { x0p = fp[0]; x1p = fp[1]; x2p = fp[2]; x3p = fp[3]; }
            else if (g == 1) { x4p = fp[4]; }
        }
        rcB = rcC;

        // pack A fragment
        uint4 Aq;
        if (g == 0)      Aq = make_uint4(pk2(x0), pk2(x1), pk2(x2), pk2(x3));
        else if (g == 1) Aq = make_uint4(pk2(x4), 0x00003F80u, 0u, 0u);   // k8,k9 | k10=1.0
        else             Aq = make_uint4(0u, 0u, 0u, 0u);
        union { uint4 q; bf16x8 v; } A; A.q = Aq;

        const unsigned L = *(const unsigned*)(lpsb + tb + (g << 2));      // 4-aligned

        const f32x4 z4 = {0.f, 0.f, 0.f, 0.f};
        f32x4 a0 = __builtin_amdgcn_mfma_f32_16x16x32_bf16(A.v, bfrag[0], z4, 0, 0, 0);
        f32x4 a1 = __builtin_amdgcn_mfma_f32_16x16x32_bf16(A.v, bfrag[1], z4, 0, 0, 0);
        f32x4 a2 = __builtin_amdgcn_mfma_f32_16x16x32_bf16(A.v, bfrag[2], z4, 0, 0, 0);
        f32x4 a3 = __builtin_amdgcn_mfma_f32_16x16x32_bf16(A.v, bfrag[3], z4, 0, 0, 0);

        // segmented pre-reduce over this lane's 4 consecutive sorted rows
        const int lp0 = (int)(L & 255u), lp1 = (int)((L >> 8) & 255u),
                  lp2 = (int)((L >> 16) & 255u), lp3 = (int)((L >> 24) & 255u);
        float m0 = a0[0], m1 = a1[0], m2 = a2[0], m3 = a3[0];
        int cp = lp0;
#define FLUSHM() { \
        unsigned* rowp = &smax[((unsigned)cp) << 6]; \
        const unsigned rb = (unsigned)(c0 + cp); \
        atomicMax(&rowp[(rb      ) & 63u], __float_as_uint(fmaxf(m0, 0.f))); \
        atomicMax(&rowp[(rb + 16u) & 63u], __float_as_uint(fmaxf(m1, 0.f))); \
        atomicMax(&rowp[(rb + 32u) & 63u], __float_as_uint(fmaxf(m2, 0.f))); \
        atomicMax(&rowp[(rb + 48u) & 63u], __float_as_uint(fmaxf(m3, 0.f))); }
        if (lp1 == cp) { m0 = fmaxf(m0, a0[1]); m1 = fmaxf(m1, a1[1]); m2 = fmaxf(m2, a2[1]); m3 = fmaxf(m3, a3[1]); }
        else { FLUSHM(); m0 = a0[1]; m1 = a1[1]; m2 = a2[1]; m3 = a3[1]; cp = lp1; }
        if (lp2 == cp) { m0 = fmaxf(m0, a0[2]); m1 = fmaxf(m1, a1[2]); m2 = fmaxf(m2, a2[2]); m3 = fmaxf(m3, a3[2]); }
        else { FLUSHM(); m0 = a0[2]; m1 = a1[2]; m2 = a2[2]; m3 = a3[2]; cp = lp2; }
        if (lp3 == cp) { m0 = fmaxf(m0, a0[3]); m1 = fmaxf(m1, a1[3]); m2 = fmaxf(m2, a2[3]); m3 = fmaxf(m3, a3[3]); }
        else { FLUSHM(); m0 = a0[3]; m1 = a1[3]; m2 = a2[3]; m3 = a3[3]; cp = lp3; }
        FLUSHM();
#undef FLUSHM
    }
    __syncthreads();

    // writeout: un-rotate by reading word (lane+row)&63; NT stores keep L2
    // capacity for the gather's shared pts lines.
    for (int row = w; row < BPF; row += 16) {
        const int gp = b * BPF + row;
        if (gp < M) {
            const float v = __uint_as_float(smax[row * 64 + ((lane + row) & 63)]);
            __builtin_nontemporal_store(v, &out[(size_t)gp * C_OUT + lane]);
        }
    }

    // overflow (T > MAXT): cold path, practically never taken
    if (T > MAXT) {
        __syncthreads();
        for (int r = MAXT + w; r < T; r += 16) {
            const unsigned rc = rec[base + r];
            const float* fp = pts + (size_t)(rc & 0x3FFFFFu) * C_IN;
            float h = 0.f;
#pragma unroll
            for (int j = 0; j < C_IN; ++j) h = fmaf(fp[j], W[j * C_OUT + lane], h);
            const float sc = gamma[lane] * rsqrtf(var[lane] + BN_EPS);
            h = fmaxf(fmaf(h, sc, fmaf(-mean[lane], sc, beta[lane])), 0.f);
            const int gp = b * BPF + (int)(rc >> 22);
            atomicMax((unsigned*)&out[(size_t)gp * C_OUT + lane], __float_as_uint(h));
        }
    }
}

// ===========================================================================
// FALLBACK: global atomic scatter (round-0)
// ===========================================================================
__global__ __launch_bounds__(256) void zero_out_kernel(float4* __restrict__ out4, int n4) {
    int i = blockIdx.x * blockDim.x + threadIdx.x;
    int stride = gridDim.x * blockDim.x;
    float4 z = make_float4(0.f, 0.f, 0.f, 0.f);
    for (int j = i; j < n4; j += stride) out4[j] = z;
}

__global__ __launch_bounds__(256) void pillar_scatter_kernel(
    const float* __restrict__ pts, const int* __restrict__ idx,
    const float* __restrict__ W, const float* __restrict__ gamma,
    const float* __restrict__ beta, const float* __restrict__ mean,
    const float* __restrict__ var, unsigned int* __restrict__ out, int npoints)
{
    const int lane = threadIdx.x & 63;
    float wv[C_IN];
#pragma unroll
    for (int j = 0; j < C_IN; ++j) wv[j] = W[j * C_OUT + lane];
    const float scale = gamma[lane] * rsqrtf(var[lane] + BN_EPS);
    const float shift = fmaf(-mean[lane], scale, beta[lane]);
    const int wave_id = (blockIdx.x * blockDim.x + threadIdx.x) >> 6;
    const int nwaves  = (gridDim.x * blockDim.x) >> 6;
    for (int p = wave_id; p < npoints; p += nwaves) {
        const float* f = pts + (size_t)p * C_IN;
        float h = 0.f;
#pragma unroll
        for (int j = 0; j < C_IN; ++j) h = fmaf(f[j], wv[j], h);
        h = fmaxf(fmaf(h, scale, shift), 0.f);
        atomicMax(&out[(size_t)idx[p] * C_OUT + lane], __float_as_uint(h));
    }
}

// ===========================================================================

extern "C" void kernel_launch(void* const* d_in, const int* in_sizes, int n_in,
                              void* d_out, int out_size, void* d_ws, size_t ws_size,
                              hipStream_t stream) {
    const float* pts   = (const float*)d_in[0];
    const int*   idx   = (const int*)  d_in[1];
    const float* W     = (const float*)d_in[2];
    const float* gamma = (const float*)d_in[3];
    const float* beta  = (const float*)d_in[4];
    const float* mean  = (const float*)d_in[5];
    const float* var   = (const float*)d_in[6];

    const int npoints = in_sizes[0] / C_IN;     // 3,000,000
    const int M       = out_size / C_OUT;       // 600,000
    const int NB      = (M + BPF - 1) / BPF;    // 2344
    const int G       = NB * CB;                // 600K
    const int nt      = (G + TS - 1) / TS;      // 294
    const int chunk   = (npoints + CB - 1) / CB;

    // ws layout (u32): ghist[G] | tsum[nt] | bstart[NB+1] | pad | rec[n]
    const size_t head_u32 = (size_t)G + (size_t)nt + (size_t)NB + 1;
    const size_t head_b   = ((head_u32 * 4) + 63) & ~(size_t)63;
    const size_t need     = head_b + (size_t)npoints * 4;

    if (NB <= NBMAX && npoints < (1 << 22) && nt <= 65535 && ws_size >= need) {
        unsigned* ghist  = (unsigned*)d_ws;
        unsigned* tsum   = ghist + G;
        unsigned* bstart = tsum + nt;
        unsigned* rec    = (unsigned*)((char*)d_ws + head_b);

        k1_hist        <<<CB, 1024, 0, stream>>>(idx, npoints, chunk, ghist, NB, 8);
        k2a_reduce     <<<nt, 256,  0, stream>>>(ghist, G, tsum);
        k2b_scan       <<<1,  256,  0, stream>>>(tsum, nt);
        k2c_apply      <<<nt, 256,  0, stream>>>(ghist, G, tsum, bstart, NB, npoints);
        k3_scatter     <<<CB, 1024, 0, stream>>>(idx, npoints, chunk, ghist, rec, NB, 8, 255u);
        pool_sfm_kernel<<<NB, 1024, 0, stream>>>(pts, rec, bstart, W, gamma, beta,
                                                 mean, var, (float*)d_out, M);
        return;
    }

    // fallback: global atomics
    zero_out_kernel<<<2048, 256, 0, stream>>>((float4*)d_out, out_size / 4);
    pillar_scatter_kernel<<<2048, 256, 0, stream>>>(
        pts, idx, W, gamma, beta, mean, var, (unsigned int*)d_out, npoints);
}